// Round 6
// baseline (363.232 us; speedup 1.0000x reference)
//
#include <hip/hip_runtime.h>
#include <hip/hip_bf16.h>
#include <cstdint>
#include <cstddef>

#define N_NODES 100000
#define N_EDGES 1600000
#define E_TOT   (N_EDGES + N_NODES)
#define F_IN    512
#define HEADS   8
#define HID     8
#define F_H     64          // HEADS*HID
#define NC      40
#define NEG     0.2f

#define BSH    8            // bucket = dst >> 8 (256 nodes/bucket)
#define NB     391          // ceil(100000/256)
#define CHUNK  8192         // edges per k_bhist/k_bfill block
#define NBLK_E ((E_TOT + CHUNK - 1) / CHUNK)   // 208
#define CAP    7168         // k_cfill LDS staging entries (avg seg ~4350)

typedef __attribute__((ext_vector_type(8))) __bf16 bf16x8;
typedef __attribute__((ext_vector_type(4))) float f32x4;
typedef __attribute__((ext_vector_type(8))) unsigned short u16x8;

__device__ __forceinline__ float bf2f(unsigned short u) {
  unsigned int w = ((unsigned int)u) << 16;
  return __builtin_bit_cast(float, w);
}
__device__ __forceinline__ unsigned short f2bf(float f) {
  __hip_bfloat16 b = __float2bfloat16(f);
  return __builtin_bit_cast(unsigned short, b);
}
__device__ __forceinline__ float lrexp(float v) {
  v = (v > 0.f) ? v : NEG * v;
  return __expf(v);
}

// ---------------------------------------------------------------------------
// edge_index dtype probe: int64 -> every odd int32 word of first entries is 0.
// ---------------------------------------------------------------------------
__global__ void k_detect(const int* __restrict__ ei, int* __restrict__ flag) {
  if (threadIdx.x == 0 && blockIdx.x == 0) {
    int nz = 0;
    for (int i = 0; i < 256; ++i) nz |= ei[2 * i + 1];
    *flag = (nz == 0) ? 1 : 0;
  }
}

__device__ __forceinline__ int load_dst(const int* __restrict__ ei, bool f, int i) {
  if (i < N_EDGES) return f ? ei[2 * (N_EDGES + i)] : ei[N_EDGES + i];
  return i - N_EDGES;
}
__device__ __forceinline__ int load_src(const int* __restrict__ ei, bool f, int i) {
  if (i < N_EDGES) return f ? ei[2 * i] : ei[i];
  return i - N_EDGES;
}

// ---------------------------------------------------------------------------
// Bucket histogram (LDS-binned, one global atomic per block-bucket).
// ---------------------------------------------------------------------------
__global__ __launch_bounds__(256) void k_bhist(const int* __restrict__ ei,
                                               const int* __restrict__ flag,
                                               int* __restrict__ bcnt) {
  __shared__ int h[NB];
  const int t = threadIdx.x;
  for (int i = t; i < NB; i += 256) h[i] = 0;
  __syncthreads();
  const bool f = (*flag) != 0;
  const int base = blockIdx.x * CHUNK;
#pragma unroll
  for (int j = 0; j < CHUNK / 256; ++j) {
    int i = base + t + j * 256;
    if (i < E_TOT) atomicAdd(&h[load_dst(ei, f, i) >> BSH], 1);
  }
  __syncthreads();
  for (int i = t; i < NB; i += 256)
    if (h[i]) atomicAdd(&bcnt[i], h[i]);
}

// ---------------------------------------------------------------------------
// Bucket exclusive scan (391 values, one block). Also seeds bcur and tails.
// ---------------------------------------------------------------------------
__global__ __launch_bounds__(512) void k_bscan(const int* __restrict__ bcnt,
                                               int* __restrict__ bstart,
                                               int* __restrict__ bcur,
                                               int* __restrict__ rowstart) {
  __shared__ int sh[512];
  const int t = threadIdx.x;
  int v = (t < NB) ? bcnt[t] : 0;
  sh[t] = v;
  __syncthreads();
  for (int d = 1; d < 512; d <<= 1) {
    int u = (t >= d) ? sh[t - d] : 0;
    __syncthreads();
    sh[t] += u;
    __syncthreads();
  }
  if (t < NB) {
    int e = sh[t] - v;
    bstart[t] = e;
    bcur[t] = e;
  }
  if (t == 0) { bstart[NB] = E_TOT; rowstart[N_NODES] = E_TOT; }
}

// ---------------------------------------------------------------------------
// Pass 1: bin CHUNK edges in LDS by bucket, flush contiguous per-bucket runs.
// Entry packing: (dst&255)<<24 | src.
// ---------------------------------------------------------------------------
__global__ __launch_bounds__(256) void k_bfill(const int* __restrict__ ei,
                                               const int* __restrict__ flag,
                                               int* __restrict__ bcur,
                                               unsigned int* __restrict__ inter) {
  __shared__ unsigned int ent[CHUNK];                 // 32 KB
  __shared__ int h[NB], ofs[NB], cur[NB], gpos[NB];   // ~6.3 KB
  const int t = threadIdx.x;
  const int base = blockIdx.x * CHUNK;
  const bool f = (*flag) != 0;
  for (int i = t; i < NB; i += 256) h[i] = 0;
  __syncthreads();
#pragma unroll
  for (int j = 0; j < CHUNK / 256; ++j) {
    int i = base + t + j * 256;
    if (i < E_TOT) atomicAdd(&h[load_dst(ei, f, i) >> BSH], 1);
  }
  __syncthreads();
  if (t < 64) {
    int loc[7];
    int s = 0;
#pragma unroll
    for (int k = 0; k < 7; ++k) {
      int idx = t * 7 + k;
      int hv = (idx < NB) ? h[idx] : 0;
      loc[k] = s;
      s += hv;
    }
    int incl = s;
    for (int dd = 1; dd < 64; dd <<= 1) {
      int u = __shfl_up(incl, dd);
      if (t >= dd) incl += u;
    }
    int excl = incl - s;
#pragma unroll
    for (int k = 0; k < 7; ++k) {
      int idx = t * 7 + k;
      if (idx < NB) ofs[idx] = excl + loc[k];
    }
  }
  __syncthreads();
  for (int i = t; i < NB; i += 256) {
    cur[i] = ofs[i];
    gpos[i] = h[i] ? atomicAdd(&bcur[i], h[i]) : 0;
  }
  __syncthreads();
#pragma unroll
  for (int j = 0; j < CHUNK / 256; ++j) {
    int i = base + t + j * 256;
    if (i < E_TOT) {
      int s = load_src(ei, f, i);
      int d = load_dst(ei, f, i);
      int p = atomicAdd(&cur[d >> BSH], 1);
      ent[p] = ((unsigned int)(d & 255) << 24) | (unsigned int)s;
    }
  }
  __syncthreads();
  const int wv = t >> 6, ln = t & 63;
  for (int b = wv; b < NB; b += 4) {
    int c = h[b];
    if (!c) continue;
    int g = gpos[b], o = ofs[b];
    for (int i = ln; i < c; i += 64) inter[g + i] = ent[o + i];
  }
}

// ---------------------------------------------------------------------------
// Pass 2: one block per bucket; LDS counting sort -> csrc + cdst + rowstart.
// ---------------------------------------------------------------------------
__global__ __launch_bounds__(256) void k_cfill(const unsigned int* __restrict__ inter,
                                               const int* __restrict__ bstart,
                                               int* __restrict__ rowstart,
                                               int* __restrict__ csrc,
                                               int* __restrict__ cdst) {
  __shared__ unsigned int out_l[CAP];      // 28 KB
  __shared__ int cnt[256], sc[256], cur2[256];
  const int t = threadIdx.x;
  const int b = blockIdx.x;
  const int segStart = bstart[b];
  const int L = bstart[b + 1] - segStart;
  cnt[t] = 0;
  __syncthreads();
  for (int i = t; i < L; i += 256) atomicAdd(&cnt[inter[segStart + i] >> 24], 1);
  __syncthreads();
  sc[t] = cnt[t];
  __syncthreads();
  for (int d = 1; d < 256; d <<= 1) {
    int v = (t >= d) ? sc[t - d] : 0;
    __syncthreads();
    sc[t] += v;
    __syncthreads();
  }
  const int excl = sc[t] - cnt[t];
  cur2[t] = excl;
  const int node = (b << BSH) + t;
  if (node < N_NODES) rowstart[node] = segStart + excl;
  __syncthreads();
  if (L <= CAP) {
    for (int i = t; i < L; i += 256) {
      unsigned int e = inter[segStart + i];
      int p = atomicAdd(&cur2[e >> 24], 1);
      out_l[p] = e;
    }
    __syncthreads();
    for (int i = t; i < L; i += 256) {
      unsigned int e = out_l[i];
      csrc[segStart + i] = (int)(e & 0xFFFFFFu);
      cdst[segStart + i] = (b << BSH) + (int)(e >> 24);
    }
  } else {  // safety fallback (statistically never taken)
    for (int i = t; i < L; i += 256) {
      unsigned int e = inter[segStart + i];
      int p = atomicAdd(&cur2[e >> 24], 1);
      csrc[segStart + p] = (int)(e & 0xFFFFFFu);
      cdst[segStart + p] = (b << BSH) + (int)(e >> 24);
    }
  }
}

// ---------------------------------------------------------------------------
// W1 repack: fp32 (512x64) -> bf16 B-fragment-major for mfma_f32_16x16x32_bf16.
// ---------------------------------------------------------------------------
__global__ __launch_bounds__(256) void k_packW(const float* __restrict__ W1,
                                               uint4* __restrict__ w1f) {
  int tid = blockIdx.x * 256 + threadIdx.x;   // 0..4095
  if (tid >= 4096) return;
  int lane = tid & 63;
  int t = (tid >> 6) & 3;
  int s = tid >> 8;
  int k0 = s * 32 + ((lane >> 4) << 3);
  int col = t * 16 + (lane & 15);
  u16x8 v;
#pragma unroll
  for (int i = 0; i < 8; ++i) v[i] = f2bf(W1[(size_t)(k0 + i) * F_H + col]);
  w1f[tid] = __builtin_bit_cast(uint4, v);
}

// ---------------------------------------------------------------------------
// GEMM1 via MFMA + fused per-head attention logits. h1 stored as bf16.
// ---------------------------------------------------------------------------
__global__ __launch_bounds__(256) void k_gemm1m(
    const float* __restrict__ x, const uint4* __restrict__ w1f,
    const float* __restrict__ a_src, const float* __restrict__ a_dst,
    unsigned short* __restrict__ h1b, float* __restrict__ als,
    float* __restrict__ ald) {
  const int t = threadIdx.x;
  const int lane = t & 63;
  const int wv = t >> 6;
  const int rb = blockIdx.x * 64 + wv * 16;
  int arow = rb + (lane & 15);
  if (arow >= N_NODES) arow = N_NODES - 1;   // clamp; stores predicated
  const float* aptr = x + (size_t)arow * F_IN + ((lane >> 4) << 3);

  f32x4 acc[4];
#pragma unroll
  for (int i = 0; i < 4; ++i) acc[i] = (f32x4){0.f, 0.f, 0.f, 0.f};

#pragma unroll 4
  for (int s = 0; s < 16; ++s) {
    float4 a0 = *reinterpret_cast<const float4*>(aptr + s * 32);
    float4 a1 = *reinterpret_cast<const float4*>(aptr + s * 32 + 4);
    uint4 b0 = w1f[(s * 4 + 0) * 64 + lane];
    uint4 b1 = w1f[(s * 4 + 1) * 64 + lane];
    uint4 b2 = w1f[(s * 4 + 2) * 64 + lane];
    uint4 b3 = w1f[(s * 4 + 3) * 64 + lane];
    bf16x8 af;
    af[0] = (__bf16)a0.x; af[1] = (__bf16)a0.y;
    af[2] = (__bf16)a0.z; af[3] = (__bf16)a0.w;
    af[4] = (__bf16)a1.x; af[5] = (__bf16)a1.y;
    af[6] = (__bf16)a1.z; af[7] = (__bf16)a1.w;
    acc[0] = __builtin_amdgcn_mfma_f32_16x16x32_bf16(af, __builtin_bit_cast(bf16x8, b0), acc[0], 0, 0, 0);
    acc[1] = __builtin_amdgcn_mfma_f32_16x16x32_bf16(af, __builtin_bit_cast(bf16x8, b1), acc[1], 0, 0, 0);
    acc[2] = __builtin_amdgcn_mfma_f32_16x16x32_bf16(af, __builtin_bit_cast(bf16x8, b2), acc[2], 0, 0, 0);
    acc[3] = __builtin_amdgcn_mfma_f32_16x16x32_bf16(af, __builtin_bit_cast(bf16x8, b3), acc[3], 0, 0, 0);
  }

  const int r0 = rb + ((lane >> 4) << 2);
  const int c = lane & 15;
#pragma unroll
  for (int tt = 0; tt < 4; ++tt) {
#pragma unroll
    for (int i = 0; i < 4; ++i) {
      int r = r0 + i;
      if (r < N_NODES) h1b[(size_t)r * F_H + tt * 16 + c] = f2bf(acc[tt][i]);
    }
  }

  // fused logits
  float asw[4], adw[4];
#pragma unroll
  for (int tt = 0; tt < 4; ++tt) {
    asw[tt] = a_src[tt * 16 + c];
    adw[tt] = a_dst[tt * 16 + c];
  }
  float sp[4][4], dp[4][4];
#pragma unroll
  for (int tt = 0; tt < 4; ++tt)
#pragma unroll
    for (int i = 0; i < 4; ++i) {
      sp[tt][i] = acc[tt][i] * asw[tt];
      dp[tt][i] = acc[tt][i] * adw[tt];
    }
#pragma unroll
  for (int dd = 1; dd < 8; dd <<= 1)
#pragma unroll
    for (int tt = 0; tt < 4; ++tt)
#pragma unroll
      for (int i = 0; i < 4; ++i) {
        sp[tt][i] += __shfl_xor(sp[tt][i], dd);
        dp[tt][i] += __shfl_xor(dp[tt][i], dd);
      }
  if ((c & 7) == 0) {
    const int hb = c >> 3;
#pragma unroll
    for (int i = 0; i < 4; ++i) {
      int r = r0 + i;
      if (r < N_NODES) {
#pragma unroll
        for (int tt = 0; tt < 4; ++tt) {
          als[(size_t)r * HEADS + tt * 2 + hb] = sp[tt][i];
          ald[(size_t)r * HEADS + tt * 2 + hb] = dp[tt][i];
        }
      }
    }
  }
}

// ---------------------------------------------------------------------------
// Edge-parallel layer-1 probabilities: pE1[e][h] = exp(lrelu(als[s][h]+ald[d][h]))
// One thread per edge; als/ald are L2-resident (3.2MB).
// ---------------------------------------------------------------------------
__global__ __launch_bounds__(256) void k_elog1(
    const int* __restrict__ csrc, const int* __restrict__ cdst,
    const float* __restrict__ als, const float* __restrict__ ald,
    float* __restrict__ pE1) {
  int i = blockIdx.x * 256 + threadIdx.x;
  if (i >= E_TOT) return;
  int s = csrc[i], d = cdst[i];
  float4 s0 = *reinterpret_cast<const float4*>(&als[(size_t)s * 8]);
  float4 s1 = *reinterpret_cast<const float4*>(&als[(size_t)s * 8 + 4]);
  float4 d0 = *reinterpret_cast<const float4*>(&ald[(size_t)d * 8]);
  float4 d1 = *reinterpret_cast<const float4*>(&ald[(size_t)d * 8 + 4]);
  float4 p0, p1;
  p0.x = lrexp(s0.x + d0.x); p0.y = lrexp(s0.y + d0.y);
  p0.z = lrexp(s0.z + d0.z); p0.w = lrexp(s0.w + d0.w);
  p1.x = lrexp(s1.x + d1.x); p1.y = lrexp(s1.y + d1.y);
  p1.z = lrexp(s1.z + d1.z); p1.w = lrexp(s1.w + d1.w);
  *reinterpret_cast<float4*>(&pE1[(size_t)i * 8]) = p0;
  *reinterpret_cast<float4*>(&pE1[(size_t)i * 8 + 4]) = p1;
}

// ---------------------------------------------------------------------------
// Layer-1 aggregation: wave = node; half-wave = edge slot; lane q = 2 features.
// 2 edges/iteration, unrolled x2 (4 edges in flight). fp32 accumulate.
// ---------------------------------------------------------------------------
__global__ __launch_bounds__(256) void k_agg1(
    const int* __restrict__ rowstart, const int* __restrict__ csrc,
    const float* __restrict__ pE1, const unsigned short* __restrict__ h1b,
    const float* __restrict__ b1, unsigned short* __restrict__ hactb) {
  int wid = (int)((blockIdx.x * 256 + threadIdx.x) >> 6);
  int lane = threadIdx.x & 63;
  if (wid >= N_NODES) return;
  const int e0 = rowstart[wid], e1 = rowstart[wid + 1];
  const int half = lane >> 5;
  const int q = lane & 31;          // features 2q, 2q+1
  const int hh = q >> 2;            // head

  float denom = 0.f, ax = 0.f, ay = 0.f;
  int e = e0 + half;
  for (; e + 2 < e1; e += 4) {
    int sA = csrc[e], sB = csrc[e + 2];
    float pA = pE1[(size_t)e * 8 + hh];
    float pB = pE1[(size_t)(e + 2) * 8 + hh];
    unsigned int uA = *reinterpret_cast<const unsigned int*>(&h1b[(size_t)sA * F_H + q * 2]);
    unsigned int uB = *reinterpret_cast<const unsigned int*>(&h1b[(size_t)sB * F_H + q * 2]);
    ax += pA * bf2f((unsigned short)uA) + pB * bf2f((unsigned short)uB);
    ay += pA * bf2f((unsigned short)(uA >> 16)) + pB * bf2f((unsigned short)(uB >> 16));
    denom += pA + pB;
  }
  if (e < e1) {
    int s = csrc[e];
    float p = pE1[(size_t)e * 8 + hh];
    unsigned int u = *reinterpret_cast<const unsigned int*>(&h1b[(size_t)s * F_H + q * 2]);
    ax += p * bf2f((unsigned short)u);
    ay += p * bf2f((unsigned short)(u >> 16));
    denom += p;
  }
  ax += __shfl_xor(ax, 32);
  ay += __shfl_xor(ay, 32);
  denom += __shfl_xor(denom, 32);
  if (half == 0) {
    float2 bb = *reinterpret_cast<const float2*>(&b1[q * 2]);
    float ox = ax / denom + bb.x;
    float oy = ay / denom + bb.y;
    ox = (ox > 0.f) ? ox : expm1f(ox);
    oy = (oy > 0.f) ? oy : expm1f(oy);
    unsigned int w = ((unsigned int)f2bf(oy) << 16) | (unsigned int)f2bf(ox);
    *reinterpret_cast<unsigned int*>(&hactb[(size_t)wid * F_H + q * 2]) = w;
  }
}

// ---------------------------------------------------------------------------
// Layer-2 projection: h2 = hact @ W2 (64x40) + attention logits (1 head).
// ---------------------------------------------------------------------------
__global__ __launch_bounds__(256) void k_l2proj(
    const unsigned short* __restrict__ hactb, const float* __restrict__ W2,
    const float* __restrict__ a_src2, const float* __restrict__ a_dst2,
    unsigned short* __restrict__ h2b, float* __restrict__ als2,
    float* __restrict__ ald2) {
  __shared__ float hs[64 * 68];
  __shared__ float w2s[F_H * NC];
  const int t = threadIdx.x;
  const int nb = blockIdx.x * 64;
  {
    int r0 = t >> 3, c8 = t & 7;
#pragma unroll
    for (int i = 0; i < 2; ++i) {
      int r = r0 + i * 32;
      int gr = nb + r;
      u16x8 v = (u16x8)(0);
      if (gr < N_NODES)
        v = *reinterpret_cast<const u16x8*>(&hactb[(size_t)gr * F_H + c8 * 8]);
#pragma unroll
      for (int k = 0; k < 8; ++k) hs[r * 68 + c8 * 8 + k] = bf2f(v[k]);
    }
  }
  for (int i = t; i < F_H * NC; i += 256) w2s[i] = W2[i];
  __syncthreads();

  const int node = t >> 2, cg = t & 3;
  float acc[10];
#pragma unroll
  for (int c = 0; c < 10; ++c) acc[c] = 0.f;
  for (int k = 0; k < F_H; ++k) {
    float xv = hs[node * 68 + k];
#pragma unroll
    for (int c = 0; c < 10; ++c) acc[c] += xv * w2s[k * NC + cg * 10 + c];
  }
  const int gn = nb + node;
  float ps = 0.f, pd = 0.f;
#pragma unroll
  for (int c = 0; c < 10; ++c) {
    ps += acc[c] * a_src2[cg * 10 + c];
    pd += acc[c] * a_dst2[cg * 10 + c];
  }
  ps += __shfl_xor(ps, 1); ps += __shfl_xor(ps, 2);
  pd += __shfl_xor(pd, 1); pd += __shfl_xor(pd, 2);
  if (gn < N_NODES) {
#pragma unroll
    for (int c = 0; c < 10; ++c) h2b[(size_t)gn * NC + cg * 10 + c] = f2bf(acc[c]);
    if (cg == 0) { als2[gn] = ps; ald2[gn] = pd; }
  }
}

// ---------------------------------------------------------------------------
// Edge-parallel layer-2 probabilities.
// ---------------------------------------------------------------------------
__global__ __launch_bounds__(256) void k_elog2(
    const int* __restrict__ csrc, const int* __restrict__ cdst,
    const float* __restrict__ als2, const float* __restrict__ ald2,
    float* __restrict__ pE2) {
  int i = blockIdx.x * 256 + threadIdx.x;
  if (i >= E_TOT) return;
  pE2[i] = lrexp(als2[csrc[i]] + ald2[cdst[i]]);
}

// ---------------------------------------------------------------------------
// Layer-2 aggregation + bias + log_softmax. Half-wave = edge slot;
// lanes q<20 hold 2 classes each.
// ---------------------------------------------------------------------------
__global__ __launch_bounds__(256) void k_agg2(
    const int* __restrict__ rowstart, const int* __restrict__ csrc,
    const float* __restrict__ pE2, const unsigned short* __restrict__ h2b,
    const float* __restrict__ b2, float* __restrict__ out) {
  int wid = (int)((blockIdx.x * 256 + threadIdx.x) >> 6);
  int lane = threadIdx.x & 63;
  if (wid >= N_NODES) return;
  const int e0 = rowstart[wid], e1 = rowstart[wid + 1];
  const int half = lane >> 5;
  const int q = lane & 31;
  const bool act = (q < 20);
  const int fo = act ? q * 2 : 0;

  float denom = 0.f, ax = 0.f, ay = 0.f;
  int e = e0 + half;
  for (; e + 2 < e1; e += 4) {
    int sA = csrc[e], sB = csrc[e + 2];
    float pA = pE2[e], pB = pE2[e + 2];
    unsigned int uA = *reinterpret_cast<const unsigned int*>(&h2b[(size_t)sA * NC + fo]);
    unsigned int uB = *reinterpret_cast<const unsigned int*>(&h2b[(size_t)sB * NC + fo]);
    ax += pA * bf2f((unsigned short)uA) + pB * bf2f((unsigned short)uB);
    ay += pA * bf2f((unsigned short)(uA >> 16)) + pB * bf2f((unsigned short)(uB >> 16));
    denom += pA + pB;
  }
  if (e < e1) {
    int s = csrc[e];
    float p = pE2[e];
    unsigned int u = *reinterpret_cast<const unsigned int*>(&h2b[(size_t)s * NC + fo]);
    ax += p * bf2f((unsigned short)u);
    ay += p * bf2f((unsigned short)(u >> 16));
    denom += p;
  }
  ax += __shfl_xor(ax, 32);
  ay += __shfl_xor(ay, 32);
  denom += __shfl_xor(denom, 32);

  float ox = -1e30f, oy = -1e30f;
  if (act) {
    float2 bb = *reinterpret_cast<const float2*>(&b2[q * 2]);
    ox = ax / denom + bb.x;
    oy = ay / denom + bb.y;
  }
  float mx = fmaxf(ox, oy);
#pragma unroll
  for (int d = 1; d < 32; d <<= 1) mx = fmaxf(mx, __shfl_xor(mx, d));
  float se = act ? (__expf(ox - mx) + __expf(oy - mx)) : 0.f;
#pragma unroll
  for (int d = 1; d < 32; d <<= 1) se += __shfl_xor(se, d);
  if (half == 0 && act) {
    float ls = __logf(se);
    float2 r;
    r.x = (ox - mx) - ls;
    r.y = (oy - mx) - ls;
    *reinterpret_cast<float2*>(&out[(size_t)wid * NC + q * 2]) = r;
  }
}

// ---------------------------------------------------------------------------
extern "C" void kernel_launch(void* const* d_in, const int* in_sizes, int n_in,
                              void* d_out, int out_size, void* d_ws, size_t ws_size,
                              hipStream_t stream) {
  const float* x      = (const float*)d_in[0];
  const int*   ei     = (const int*)d_in[1];
  const float* W1     = (const float*)d_in[2];
  const float* a_src1 = (const float*)d_in[3];
  const float* a_dst1 = (const float*)d_in[4];
  const float* b1     = (const float*)d_in[5];
  const float* W2     = (const float*)d_in[6];
  const float* a_src2 = (const float*)d_in[7];
  const float* a_dst2 = (const float*)d_in[8];
  const float* b2     = (const float*)d_in[9];
  float* out = (float*)d_out;

  char* ws = (char*)d_ws;
  size_t o = 0;
  auto carve = [&](size_t bytes) -> char* {
    char* p = ws + o;
    o = (o + bytes + 255) & ~(size_t)255;
    return p;
  };
  int*   flag     = (int*)carve(256);
  int*   bcnt     = (int*)carve((size_t)NB * 4);
  int*   bstart   = (int*)carve((size_t)(NB + 1) * 4);
  int*   bcur     = (int*)carve((size_t)NB * 4);
  int*   rowstart = (int*)carve((size_t)(N_NODES + 1) * 4);
  unsigned int* inter = (unsigned int*)carve((size_t)E_TOT * 4);
  int*   csrc     = (int*)carve((size_t)E_TOT * 4);
  int*   cdst     = (int*)carve((size_t)E_TOT * 4);
  uint4* w1f      = (uint4*)carve((size_t)4096 * 16);
  unsigned short* h1b   = (unsigned short*)carve((size_t)N_NODES * F_H * 2);
  float* als1     = (float*)carve((size_t)N_NODES * HEADS * 4);
  float* ald1     = (float*)carve((size_t)N_NODES * HEADS * 4);
  unsigned short* hactb = (unsigned short*)carve((size_t)N_NODES * F_H * 2);
  unsigned short* h2b   = (unsigned short*)carve((size_t)N_NODES * NC * 2);
  float* als2     = (float*)carve((size_t)N_NODES * 4);
  float* ald2     = (float*)carve((size_t)N_NODES * 4);
  float* pE1      = (float*)carve((size_t)E_TOT * 8 * 4);
  float* pE2      = (float*)carve((size_t)E_TOT * 4);
  (void)ws_size; (void)n_in; (void)in_sizes; (void)out_size;

  hipMemsetAsync(bcnt, 0, (size_t)NB * 4, stream);
  k_detect<<<1, 64, 0, stream>>>(ei, flag);
  k_bhist<<<NBLK_E, 256, 0, stream>>>(ei, flag, bcnt);
  k_bscan<<<1, 512, 0, stream>>>(bcnt, bstart, bcur, rowstart);
  k_bfill<<<NBLK_E, 256, 0, stream>>>(ei, flag, bcur, inter);
  k_cfill<<<NB, 256, 0, stream>>>(inter, bstart, rowstart, csrc, cdst);

  k_packW<<<16, 256, 0, stream>>>(W1, w1f);
  k_gemm1m<<<(N_NODES + 63) / 64, 256, 0, stream>>>(x, w1f, a_src1, a_dst1, h1b, als1, ald1);

  const int egrid = (E_TOT + 255) / 256;
  k_elog1<<<egrid, 256, 0, stream>>>(csrc, cdst, als1, ald1, pE1);
  k_agg1<<<(N_NODES * 64 + 255) / 256, 256, 0, stream>>>(rowstart, csrc, pE1, h1b, b1, hactb);
  k_l2proj<<<(N_NODES + 63) / 64, 256, 0, stream>>>(hactb, W2, a_src2, a_dst2, h2b, als2, ald2);
  k_elog2<<<egrid, 256, 0, stream>>>(csrc, cdst, als2, ald2, pE2);
  k_agg2<<<(N_NODES * 64 + 255) / 256, 256, 0, stream>>>(rowstart, csrc, pE2, h2b, b2, out);
}